// Round 1
// baseline (139.491 us; speedup 1.0000x reference)
//
#include <hip/hip_runtime.h>

#define B 8
#define C 512
#define D 2048   // T*H*W
#define L 2049   // D+1
#define NH 8
#define CH 64

__device__ __forceinline__ float wave_reduce_sum(float v) {
  #pragma unroll
  for (int off = 32; off; off >>= 1) v += __shfl_down(v, off);
  return v;
}

// Pass 1: mean over the 2048 contiguous spatial positions per (b,c) row.
__global__ void __launch_bounds__(256) k_mean(const float* __restrict__ x, float* __restrict__ mean) {
  int row = blockIdx.x;  // b*C + c
  const float4* xr = reinterpret_cast<const float4*>(x + (size_t)row * D);
  float s = 0.f;
  #pragma unroll
  for (int i = 0; i < 2; ++i) {
    float4 v = xr[threadIdx.x + i * 256];
    s += (v.x + v.y) + (v.z + v.w);
  }
  __shared__ float red[4];
  s = wave_reduce_sum(s);
  if ((threadIdx.x & 63) == 0) red[threadIdx.x >> 6] = s;
  __syncthreads();
  if (threadIdx.x == 0) mean[row] = (red[0] + red[1] + red[2] + red[3]) * (1.0f / D);
}

// q0[b,o] = W_q[o,:]·(mean[b,:]+pos[:,0]) + b_qkv[o]   (one wave per output)
__global__ void __launch_bounds__(256) k_q0(const float* __restrict__ wqkv, const float* __restrict__ bqkv,
                                            const float* __restrict__ pos, const float* __restrict__ mean,
                                            float* __restrict__ q0) {
  int gw = blockIdx.x * 4 + (threadIdx.x >> 6);
  int lane = threadIdx.x & 63;
  int b = gw >> 9;
  int o = gw & 511;
  float acc = 0.f;
  for (int c = lane; c < C; c += 64)
    acc += wqkv[(size_t)o * C + c] * (mean[b * C + c] + pos[(size_t)c * L]);
  acc = wave_reduce_sum(acc);
  if (lane == 0) q0[b * C + o] = acc + bqkv[o];
}

// u[b,h,c] = (1/8)·Σ_j q0[b,h*64+j]·W_k[h*64+j, c];  beta[b,h] = (1/8)·q0_h·b_k_h
__global__ void __launch_bounds__(256) k_u(const float* __restrict__ wqkv, const float* __restrict__ bqkv,
                                           const float* __restrict__ q0, float* __restrict__ u,
                                           float* __restrict__ beta) {
  int bh = blockIdx.x;
  int b = bh >> 3, h = bh & 7;
  __shared__ float q0s[CH];
  if (threadIdx.x < CH) q0s[threadIdx.x] = q0[b * C + h * CH + threadIdx.x];
  __syncthreads();
  const float sc = 0.125f;  // scale^2 = 1/sqrt(64)
  for (int c = threadIdx.x; c < C; c += 256) {
    float acc = 0.f;
    #pragma unroll 8
    for (int j = 0; j < CH; ++j)
      acc += q0s[j] * wqkv[(size_t)(C + h * CH + j) * C + c];
    u[(size_t)bh * C + c] = acc * sc;
  }
  if (threadIdx.x == 0) {
    float acc = 0.f;
    for (int j = 0; j < CH; ++j) acc += q0s[j] * bqkv[C + h * CH + j];
    beta[bh] = acc * sc;
  }
}

// Pass 2: logits[b,h,l] = u[b,h,:]·xf[b,:,l] + beta[b,h].
// One wave per 64 consecutive l; lanes coalesce along l; u loads are wave-uniform.
__global__ void __launch_bounds__(64) k_logits(const float* __restrict__ x, const float* __restrict__ pos,
                                               const float* __restrict__ mean, const float* __restrict__ u,
                                               const float* __restrict__ beta, float* __restrict__ logits) {
  int b = blockIdx.y;
  int l = blockIdx.x * 64 + threadIdx.x;
  if (l >= L) return;
  const float* xp;
  int stride;
  if (l == 0) { xp = mean + b * C; stride = 1; }        // xf[:,0] = mean + pos[:,0]
  else        { xp = x + (size_t)b * C * D + (l - 1); stride = D; }
  const float* pp = pos + l;
  const float* ub = u + (size_t)b * NH * C;
  float a[NH];
  #pragma unroll
  for (int h = 0; h < NH; ++h) a[h] = 0.f;
  for (int c = 0; c < C; ++c) {
    float xv = *xp + *pp;
    xp += stride; pp += L;
    #pragma unroll
    for (int h = 0; h < NH; ++h) a[h] += ub[h * C + c] * xv;
  }
  #pragma unroll
  for (int h = 0; h < NH; ++h)
    logits[(size_t)(b * NH + h) * L + l] = a[h] + beta[b * NH + h];
}

// Softmax over l per (b,h); in place.
__global__ void __launch_bounds__(256) k_softmax(float* __restrict__ wlog) {
  __shared__ float red[4];
  __shared__ float bcast;
  float* row = wlog + (size_t)blockIdx.x * L;
  int tid = threadIdx.x;
  int lane = tid & 63, wid = tid >> 6;
  float m = -3.0e38f;
  for (int l = tid; l < L; l += 256) m = fmaxf(m, row[l]);
  #pragma unroll
  for (int off = 32; off; off >>= 1) m = fmaxf(m, __shfl_down(m, off));
  if (lane == 0) red[wid] = m;
  __syncthreads();
  if (tid == 0) bcast = fmaxf(fmaxf(red[0], red[1]), fmaxf(red[2], red[3]));
  __syncthreads();
  float M = bcast;
  float s = 0.f;
  for (int l = tid; l < L; l += 256) { float e = __expf(row[l] - M); row[l] = e; s += e; }
  #pragma unroll
  for (int off = 32; off; off >>= 1) s += __shfl_down(s, off);
  __syncthreads();
  if (lane == 0) red[wid] = s;
  __syncthreads();
  if (tid == 0) bcast = red[0] + red[1] + red[2] + red[3];
  __syncthreads();
  float inv = 1.0f / bcast;
  for (int l = tid; l < L; l += 256) row[l] *= inv;
}

// Pass 3: xbar[b,h,c] = Σ_l w[b,h,l]·xf[b,c,l].  One wave per (b,c); x row contiguous.
__global__ void __launch_bounds__(256) k_xbar(const float* __restrict__ x, const float* __restrict__ pos,
                                              const float* __restrict__ mean, const float* __restrict__ w,
                                              float* __restrict__ xbar) {
  int gw = blockIdx.x * 4 + (threadIdx.x >> 6);
  int lane = threadIdx.x & 63;
  int b = gw >> 9;
  int c = gw & 511;
  const float* xr = x + (size_t)(b * C + c) * D;
  const float* pr = pos + (size_t)c * L;
  const float* wb = w + (size_t)b * NH * L;
  float acc[NH];
  #pragma unroll
  for (int h = 0; h < NH; ++h) acc[h] = 0.f;
  for (int i = lane; i < D; i += 64) {
    float xv = xr[i];
    #pragma unroll
    for (int h = 0; h < NH; ++h) acc[h] += wb[h * L + i + 1] * xv;
  }
  for (int i = lane; i < L; i += 64) {
    float pv = pr[i];
    #pragma unroll
    for (int h = 0; h < NH; ++h) acc[h] += wb[h * L + i] * pv;
  }
  if (lane == 0) {
    float mv = mean[b * C + c];
    #pragma unroll
    for (int h = 0; h < NH; ++h) acc[h] += wb[h * L] * mv;
  }
  #pragma unroll
  for (int h = 0; h < NH; ++h) acc[h] = wave_reduce_sum(acc[h]);
  if (lane == 0) {
    #pragma unroll
    for (int h = 0; h < NH; ++h) xbar[(size_t)(b * NH + h) * C + c] = acc[h];
  }
}

// a0[b,cv] = W_v[cv,:]·xbar[b,head(cv),:] + b_v[cv]   (weights sum to 1 so bias passes through)
__global__ void __launch_bounds__(256) k_a0(const float* __restrict__ wqkv, const float* __restrict__ bqkv,
                                            const float* __restrict__ xbar, float* __restrict__ a0) {
  int gw = blockIdx.x * 4 + (threadIdx.x >> 6);
  int lane = threadIdx.x & 63;
  int b = gw >> 9;
  int cv = gw & 511;
  int h = cv >> 6;
  float acc = 0.f;
  const float* wr = wqkv + (size_t)(2 * C + cv) * C;
  const float* xb = xbar + (size_t)(b * NH + h) * C;
  for (int c = lane; c < C; c += 64) acc += wr[c] * xb[c];
  acc = wave_reduce_sum(acc);
  if (lane == 0) a0[b * C + cv] = acc + bqkv[2 * C + cv];
}

// out[b,o] = W_c[o,:]·a0[b,:] + b_c[o]
__global__ void __launch_bounds__(256) k_out(const float* __restrict__ wc, const float* __restrict__ bc,
                                             const float* __restrict__ a0, float* __restrict__ out) {
  int gw = blockIdx.x * 4 + (threadIdx.x >> 6);
  int lane = threadIdx.x & 63;
  int b = gw >> 9;
  int o = gw & 511;
  float acc = 0.f;
  const float* wr = wc + (size_t)o * C;
  const float* ar = a0 + b * C;
  for (int c = lane; c < C; c += 64) acc += wr[c] * ar[c];
  acc = wave_reduce_sum(acc);
  if (lane == 0) out[b * C + o] = acc + bc[o];
}

extern "C" void kernel_launch(void* const* d_in, const int* in_sizes, int n_in,
                              void* d_out, int out_size, void* d_ws, size_t ws_size,
                              hipStream_t stream) {
  const float* x    = (const float*)d_in[0];
  const float* pos  = (const float*)d_in[1];
  const float* wqkv = (const float*)d_in[2];
  const float* bqkv = (const float*)d_in[3];
  const float* wc   = (const float*)d_in[4];
  const float* bc   = (const float*)d_in[5];
  float* out = (float*)d_out;
  float* ws  = (float*)d_ws;

  float* mean = ws;             // 4096
  float* q0   = ws + 4096;      // 4096
  float* u    = ws + 8192;      // 32768
  float* beta = ws + 40960;     // 64
  float* wlog = ws + 41024;     // 64*2049 = 131136
  float* xbar = ws + 172160;    // 32768
  float* a0   = ws + 204928;    // 4096   (total 209024 floats = 836 KB)

  hipLaunchKernelGGL(k_mean,    dim3(B * C),     dim3(256), 0, stream, x, mean);
  hipLaunchKernelGGL(k_q0,      dim3(B * C / 4), dim3(256), 0, stream, wqkv, bqkv, pos, mean, q0);
  hipLaunchKernelGGL(k_u,       dim3(B * NH),    dim3(256), 0, stream, wqkv, bqkv, q0, u, beta);
  hipLaunchKernelGGL(k_logits,  dim3(33, B),     dim3(64),  0, stream, x, pos, mean, u, beta, wlog);
  hipLaunchKernelGGL(k_softmax, dim3(B * NH),    dim3(256), 0, stream, wlog);
  hipLaunchKernelGGL(k_xbar,    dim3(B * C / 4), dim3(256), 0, stream, x, pos, mean, wlog, xbar);
  hipLaunchKernelGGL(k_a0,      dim3(B * C / 4), dim3(256), 0, stream, wqkv, bqkv, xbar, a0);
  hipLaunchKernelGGL(k_out,     dim3(B * C / 4), dim3(256), 0, stream, wc, bc, a0, out);
}

// Round 2
// 69.986 us; speedup vs baseline: 1.9931x; 1.9931x over previous
//
#include <hip/hip_runtime.h>

#define B 8
#define C 512
#define D 2048   // spatial positions (l >= 1 count)
#define L 2049   // D+1
#define NH 8
#define CH 64

__device__ __forceinline__ float wave_reduce_sum(float v) {
  #pragma unroll
  for (int off = 32; off; off >>= 1) v += __shfl_down(v, off);
  return v;
}

// Pass 1: mean over 2048 contiguous spatial positions per (b,c) row.
__global__ void __launch_bounds__(256) k_mean(const float* __restrict__ x, float* __restrict__ mean) {
  int row = blockIdx.x;  // b*C + c
  const float4* xr = reinterpret_cast<const float4*>(x + (size_t)row * D);
  float s = 0.f;
  #pragma unroll
  for (int i = 0; i < 2; ++i) {
    float4 v = xr[threadIdx.x + i * 256];
    s += (v.x + v.y) + (v.z + v.w);
  }
  __shared__ float red[4];
  s = wave_reduce_sum(s);
  if ((threadIdx.x & 63) == 0) red[threadIdx.x >> 6] = s;
  __syncthreads();
  if (threadIdx.x == 0) mean[row] = (red[0] + red[1] + red[2] + red[3]) * (1.0f / D);
}

// Fused: q0 (head slice) -> u[b,h,:] -> logit0[b,h]. One block per (b,h).
// beta (bias-k term) is constant over l -> softmax-invariant -> dropped.
__global__ void __launch_bounds__(256) k_qu(const float* __restrict__ wqkv,
                                            const float* __restrict__ pos,
                                            const float* __restrict__ mean,
                                            float* __restrict__ u,
                                            float* __restrict__ logit0) {
  int bh = blockIdx.x, b = bh >> 3, h = bh & 7;
  int tid = threadIdx.x, wid = tid >> 6, lane = tid & 63;
  __shared__ float mps[C];   // mean + pos[:,0]  (= xf[:,0])
  __shared__ float q0s[CH];
  __shared__ float us[C];
  __shared__ float red[4];
  for (int c = tid; c < C; c += 256) mps[c] = mean[b * C + c] + pos[(size_t)c * L];
  __syncthreads();
  // q0[j] = W_q[h*64+j,:] . mps   (b_q omitted? NO - q bias matters: it multiplies W_k)
  // q0 must include b_qkv[h*64+j]!
  for (int j = wid; j < CH; j += 4) {
    const float* wr = wqkv + (size_t)(h * CH + j) * C;
    float acc = 0.f;
    for (int c = lane; c < C; c += 64) acc += wr[c] * mps[c];
    acc = wave_reduce_sum(acc);
    if (lane == 0) q0s[j] = acc;   // bias added below by thread 0..63
  }
  __syncthreads();
  // add q bias (b_qkv[0:512] slice for this head) -- done once
  // (wqkv arg order in launch passes bqkv via pos? No -- bqkv handled here:)
  // NOTE: bqkv pointer passed as part of u-kernel args; see kernel_launch.
  // (handled: see k_qu_bias below -- folded via extra arg)
  // -- replaced by extra parameter:
  // (see actual signature: bqkv added)
  __syncthreads();
  float a0 = 0.f, a1 = 0.f;
  for (int j = 0; j < CH; ++j) {
    float qv = q0s[j];
    const float* wkr = wqkv + (size_t)(C + h * CH + j) * C;
    a0 += qv * wkr[tid];
    a1 += qv * wkr[tid + 256];
  }
  a0 *= 0.125f; a1 *= 0.125f;
  us[tid] = a0; us[tid + 256] = a1;
  u[(size_t)bh * C + tid] = a0;
  u[(size_t)bh * C + tid + 256] = a1;
  __syncthreads();
  float p = us[tid] * mps[tid] + us[tid + 256] * mps[tid + 256];
  p = wave_reduce_sum(p);
  if (lane == 0) red[wid] = p;
  __syncthreads();
  if (tid == 0) logit0[bh] = red[0] + red[1] + red[2] + red[3];
}

// Variant with q-bias (the real one used): q0s[j] += bqkv[h*64+j]
__global__ void __launch_bounds__(256) k_qu2(const float* __restrict__ wqkv,
                                             const float* __restrict__ bqkv,
                                             const float* __restrict__ pos,
                                             const float* __restrict__ mean,
                                             float* __restrict__ u,
                                             float* __restrict__ logit0) {
  int bh = blockIdx.x, b = bh >> 3, h = bh & 7;
  int tid = threadIdx.x, wid = tid >> 6, lane = tid & 63;
  __shared__ float mps[C];
  __shared__ float q0s[CH];
  __shared__ float us[C];
  __shared__ float red[4];
  for (int c = tid; c < C; c += 256) mps[c] = mean[b * C + c] + pos[(size_t)c * L];
  __syncthreads();
  for (int j = wid; j < CH; j += 4) {
    const float* wr = wqkv + (size_t)(h * CH + j) * C;
    float acc = 0.f;
    for (int c = lane; c < C; c += 64) acc += wr[c] * mps[c];
    acc = wave_reduce_sum(acc);
    if (lane == 0) q0s[j] = acc + bqkv[h * CH + j];
  }
  __syncthreads();
  float a0 = 0.f, a1 = 0.f;
  for (int j = 0; j < CH; ++j) {
    float qv = q0s[j];
    const float* wkr = wqkv + (size_t)(C + h * CH + j) * C;
    a0 += qv * wkr[tid];
    a1 += qv * wkr[tid + 256];
  }
  a0 *= 0.125f; a1 *= 0.125f;
  us[tid] = a0; us[tid + 256] = a1;
  u[(size_t)bh * C + tid] = a0;
  u[(size_t)bh * C + tid + 256] = a1;
  __syncthreads();
  float p = us[tid] * mps[tid] + us[tid + 256] * mps[tid + 256];
  p = wave_reduce_sum(p);
  if (lane == 0) red[wid] = p;
  __syncthreads();
  if (tid == 0) logit0[bh] = red[0] + red[1] + red[2] + red[3];
}

// Pass 2: logits[b,h,l] for l>=1, high-parallelism version.
// grid (16 l-tiles of 128, B, 2 c-halves), block 256 (4 waves).
// Wave = one 64-c chunk; lane = 2 l's (float2). u staged in LDS (broadcast reads).
// 4-wave partial reduce in LDS; 2 block-level partials summed in softmax.
__global__ void __launch_bounds__(256) k_logits(const float* __restrict__ x,
                                                const float* __restrict__ pos,
                                                const float* __restrict__ u,
                                                float* __restrict__ wpart) {
  __shared__ float ulds[NH][256];
  __shared__ float rlds[4][NH][128];
  int b = blockIdx.y, bz = blockIdx.z;
  int tid = threadIdx.x, wid = tid >> 6, lane = tid & 63;
  for (int idx = tid; idx < NH * 256; idx += 256) {
    int h = idx >> 8, cc = idx & 255;
    ulds[h][cc] = u[(size_t)(b * NH + h) * C + bz * 256 + cc];
  }
  __syncthreads();
  int l0 = blockIdx.x * 128 + lane * 2;       // x column; actual l = l0 + 1
  int cg = bz * 256 + wid * 64;               // this wave's global c base
  const float* xp = x + ((size_t)(b * C + cg)) * D + l0;
  const float* pp = pos + (size_t)cg * L + l0 + 1;
  float2 acc[NH];
  #pragma unroll
  for (int h = 0; h < NH; ++h) acc[h] = make_float2(0.f, 0.f);
  #pragma unroll 4
  for (int cc = 0; cc < 64; ++cc) {
    float2 xv = *reinterpret_cast<const float2*>(xp);
    float v0 = xv.x + pp[0];
    float v1 = xv.y + pp[1];
    #pragma unroll
    for (int h = 0; h < NH; ++h) {
      float uu = ulds[h][wid * 64 + cc];
      acc[h].x += uu * v0;
      acc[h].y += uu * v1;
    }
    xp += D; pp += L;
  }
  #pragma unroll
  for (int h = 0; h < NH; ++h) {
    rlds[wid][h][lane * 2]     = acc[h].x;
    rlds[wid][h][lane * 2 + 1] = acc[h].y;
  }
  __syncthreads();
  for (int idx = tid; idx < NH * 128; idx += 256) {
    int h = idx >> 7, ll = idx & 127;
    float s = rlds[0][h][ll] + rlds[1][h][ll] + rlds[2][h][ll] + rlds[3][h][ll];
    wpart[((size_t)(bz * B * NH) + b * NH + h) * (size_t)D + blockIdx.x * 128 + ll] = s;
  }
}

// Softmax: sum 2 c-half partials + logit0, softmax over 2049, emit w0 + wrow[2048].
__global__ void __launch_bounds__(256) k_softmax(const float* __restrict__ wpart,
                                                 const float* __restrict__ logit0,
                                                 float* __restrict__ wrow,
                                                 float* __restrict__ w0) {
  int bh = blockIdx.x, tid = threadIdx.x, wid = tid >> 6, lane = tid & 63;
  __shared__ float vv[D];
  __shared__ float red[4];
  __shared__ float bc;
  const float* r0 = wpart + (size_t)bh * D;
  const float* r1 = wpart + (size_t)(B * NH + bh) * D;
  float lg0 = logit0[bh];
  float m = lg0;
  for (int i = tid; i < D; i += 256) {
    float v = r0[i] + r1[i];
    vv[i] = v;
    m = fmaxf(m, v);
  }
  #pragma unroll
  for (int off = 32; off; off >>= 1) m = fmaxf(m, __shfl_down(m, off));
  if (lane == 0) red[wid] = m;
  __syncthreads();
  if (tid == 0) bc = fmaxf(fmaxf(red[0], red[1]), fmaxf(red[2], red[3]));
  __syncthreads();
  float M = bc;
  float s = 0.f;
  for (int i = tid; i < D; i += 256) { float e = __expf(vv[i] - M); vv[i] = e; s += e; }
  float e0 = __expf(lg0 - M);
  s = wave_reduce_sum(s);
  __syncthreads();
  if (lane == 0) red[wid] = s;
  __syncthreads();
  if (tid == 0) bc = red[0] + red[1] + red[2] + red[3] + e0;
  __syncthreads();
  float inv = 1.0f / bc;
  for (int i = tid; i < D; i += 256) wrow[(size_t)bh * D + i] = vv[i] * inv;
  if (tid == 0) w0[bh] = e0 * inv;
}

// Pass 3: xbar[b,h,c] = sum_l w[b,h,l]*xf[b,c,l]. Wave = (b, 4 consecutive c),
// float4 loads of x and w; w rows shared across the 4 c in registers.
__global__ void __launch_bounds__(256) k_xbar(const float* __restrict__ x,
                                              const float* __restrict__ pos,
                                              const float* __restrict__ mean,
                                              const float* __restrict__ wrow,
                                              const float* __restrict__ w0,
                                              float* __restrict__ xbar) {
  int tid = threadIdx.x, wid = tid >> 6, lane = tid & 63;
  int gw = blockIdx.x * 4 + wid;          // 0..1023
  int b = gw >> 7;
  int c0 = (gw & 127) * 4;
  float acc[4][NH];
  #pragma unroll
  for (int cl = 0; cl < 4; ++cl)
    #pragma unroll
    for (int h = 0; h < NH; ++h) acc[cl][h] = 0.f;
  for (int it = 0; it < 8; ++it) {
    int i4 = it * 64 + lane;              // float4 index into 2048
    float4 wv[NH];
    #pragma unroll
    for (int h = 0; h < NH; ++h)
      wv[h] = reinterpret_cast<const float4*>(wrow + (size_t)(b * NH + h) * D)[i4];
    #pragma unroll
    for (int cl = 0; cl < 4; ++cl) {
      int c = c0 + cl;
      float4 xv = reinterpret_cast<const float4*>(x + (size_t)(b * C + c) * D)[i4];
      const float* pp = pos + (size_t)c * L + 1 + i4 * 4;
      float v0 = xv.x + pp[0], v1 = xv.y + pp[1], v2 = xv.z + pp[2], v3 = xv.w + pp[3];
      #pragma unroll
      for (int h = 0; h < NH; ++h)
        acc[cl][h] += wv[h].x * v0 + wv[h].y * v1 + wv[h].z * v2 + wv[h].w * v3;
    }
  }
  #pragma unroll
  for (int cl = 0; cl < 4; ++cl) {
    int c = c0 + cl;
    float m0 = (lane == 0) ? (mean[b * C + c] + pos[(size_t)c * L]) : 0.f;
    #pragma unroll
    for (int h = 0; h < NH; ++h) {
      float a = acc[cl][h] + m0 * w0[b * NH + h];
      a = wave_reduce_sum(a);
      if (lane == 0) xbar[(size_t)(b * NH + h) * C + c] = a;
    }
  }
}

// a0[b,cv] = W_v[cv,:].xbar[b,head(cv),:] + b_v[cv]  (weights sum to 1 -> bias passes through)
__global__ void __launch_bounds__(256) k_a0(const float* __restrict__ wqkv, const float* __restrict__ bqkv,
                                            const float* __restrict__ xbar, float* __restrict__ a0) {
  int gw = blockIdx.x * 4 + (threadIdx.x >> 6);
  int lane = threadIdx.x & 63;
  int b = gw >> 9;
  int cv = gw & 511;
  int h = cv >> 6;
  float acc = 0.f;
  const float* wr = wqkv + (size_t)(2 * C + cv) * C;
  const float* xb = xbar + (size_t)(b * NH + h) * C;
  for (int c = lane; c < C; c += 64) acc += wr[c] * xb[c];
  acc = wave_reduce_sum(acc);
  if (lane == 0) a0[b * C + cv] = acc + bqkv[2 * C + cv];
}

// out[b,o] = W_c[o,:].a0[b,:] + b_c[o]
__global__ void __launch_bounds__(256) k_out(const float* __restrict__ wc, const float* __restrict__ bc,
                                             const float* __restrict__ a0, float* __restrict__ out) {
  int gw = blockIdx.x * 4 + (threadIdx.x >> 6);
  int lane = threadIdx.x & 63;
  int b = gw >> 9;
  int o = gw & 511;
  float acc = 0.f;
  const float* wr = wc + (size_t)o * C;
  const float* ar = a0 + b * C;
  for (int c = lane; c < C; c += 64) acc += wr[c] * ar[c];
  acc = wave_reduce_sum(acc);
  if (lane == 0) out[b * C + o] = acc + bc[o];
}

extern "C" void kernel_launch(void* const* d_in, const int* in_sizes, int n_in,
                              void* d_out, int out_size, void* d_ws, size_t ws_size,
                              hipStream_t stream) {
  const float* x    = (const float*)d_in[0];
  const float* pos  = (const float*)d_in[1];
  const float* wqkv = (const float*)d_in[2];
  const float* bqkv = (const float*)d_in[3];
  const float* wc   = (const float*)d_in[4];
  const float* bc   = (const float*)d_in[5];
  float* out = (float*)d_out;
  float* ws  = (float*)d_ws;

  float* mean   = ws;               // 4096
  float* u      = ws + 4096;        // 32768
  float* logit0 = ws + 36864;       // 64
  float* wpart  = ws + 36928;       // 2*64*2048 = 262144
  float* wrow   = ws + 299072;      // 64*2048 = 131072
  float* w0     = ws + 430144;      // 64
  float* xbar   = ws + 430208;      // 32768
  float* a0     = ws + 462976;      // 4096  -> total 467072 floats = 1.87 MB

  hipLaunchKernelGGL(k_mean,    dim3(B * C),       dim3(256), 0, stream, x, mean);
  hipLaunchKernelGGL(k_qu2,     dim3(B * NH),      dim3(256), 0, stream, wqkv, bqkv, pos, mean, u, logit0);
  hipLaunchKernelGGL(k_logits,  dim3(16, B, 2),    dim3(256), 0, stream, x, pos, u, wpart);
  hipLaunchKernelGGL(k_softmax, dim3(B * NH),      dim3(256), 0, stream, wpart, logit0, wrow, w0);
  hipLaunchKernelGGL(k_xbar,    dim3(256),         dim3(256), 0, stream, x, pos, mean, wrow, w0, xbar);
  hipLaunchKernelGGL(k_a0,      dim3(B * C / 4),   dim3(256), 0, stream, wqkv, bqkv, xbar, a0);
  hipLaunchKernelGGL(k_out,     dim3(B * C / 4),   dim3(256), 0, stream, wc, bc, a0, out);
}